// Round 9
// baseline (420.920 us; speedup 1.0000x reference)
//
#include <hip/hip_runtime.h>
#include <hip/hip_bf16.h>

// R8. R7 mega2 (grid 1024) = 156us: occ 38% is GRID-LIMITED (4 blocks/CU
// launched; HW takes 8 at 64 VGPR/16KB LDS). WRITE 329MB vs 172 ideal is
// harness-poison writeback of d_out (~168MB) evicting during our window ->
// unavoidable; realistic floor ~78us. Single change this round (clean A/B):
// grid 1024 -> 2624 = TTOT/4 exactly (perfect 4-tiles/block balance, %8==0
// for XCD swizzle) -> 8 resident blocks/CU, latency finally hidden.

constexpr int T_ = 4, E_ = 4096, B_ = 2, D_ = 128, N_ = 384;
constexpr int EB = E_ * B_;                  // 8192 (e,b) pairs
constexpr int XSTRIDE_T = E_ * B_ * D_;      // floats between t-planes
constexpr int XROWS = T_ * EB;               // 32768 rows of x
constexpr int NROWS = N_ * N_ * B_;          // 294912 feats rows
constexpr int NCELLS = N_ * N_;              // 147456

typedef __attribute__((ext_vector_type(8))) short bf16x8;
typedef __attribute__((ext_vector_type(4))) float f32x4;
union BF8 { bf16x8 v; ushort u[8]; };

// workspace layout (float element offsets)
constexpr size_t OFF_WTG    = 0;                              // 16384
constexpr size_t OFF_WTL    = 16384;                          // 16384
constexpr size_t OFF_WTR    = 32768;                          // 16384
constexpr size_t OFF_BCOMB  = 49152;                          // 128
constexpr size_t OFF_BP     = 49280;                          // 128
constexpr size_t OFF_XMEAN  = 49408;                          // EB*D
constexpr size_t OFF_UC     = OFF_XMEAN + (size_t)EB * D_;    // EB*D
constexpr size_t OFF_WIN    = OFF_UC + (size_t)EB * D_;       // N*N ints
constexpr size_t OFF_BPACK  = OFF_WIN + (size_t)NCELLS;       // 16384 (64KB)
constexpr size_t OFF_BPACKG = OFF_BPACK + 16384;              // 16384
constexpr size_t OFF_BPACKR = OFF_BPACKG + 16384;             // 16384
constexpr size_t OFF_WGR    = OFF_BPACKR + 16384;             // 16384
constexpr size_t OFF_BGR    = OFF_WGR + 16384;                // 128
constexpr size_t WS_FLOATS  = OFF_BGR + 128;                  // ~9.5MB

static __device__ inline ushort f2bf(float x) {
  const uint u = __float_as_uint(x);
  return (ushort)((u + 0x7fffu + ((u >> 16) & 1u)) >> 16);
}
static __device__ inline float bf2f(ushort h) {
  return __uint_as_float(((uint)h) << 16);
}

// ---------------------------------------------------------------------------
// prep: W_comb halves (transposed), W_g transpose, bcomb, bp, winner init
// ---------------------------------------------------------------------------
__global__ __launch_bounds__(256) void prep_kernel(
    const float* __restrict__ W_f, const float* __restrict__ W_lin,
    const float* __restrict__ W_g, const float* __restrict__ b_lin,
    const float* __restrict__ b_f, const float* __restrict__ pad,
    float* __restrict__ WtG, float* __restrict__ WtL, float* __restrict__ WtR,
    float* __restrict__ bcomb, float* __restrict__ bp, int* __restrict__ winner) {
  const int o = blockIdx.x;    // 0..127
  const int c = threadIdx.x;   // 0..255

  for (int i = blockIdx.x * 256 + c; i < NCELLS; i += 128 * 256) winner[i] = -1;

  float acc = 0.f;
#pragma unroll 4
  for (int d = 0; d < D_; ++d) acc += W_f[o * D_ + d] * W_lin[d * (2 * D_) + c];

  if (c < D_) {
    WtL[c * D_ + o] = acc;
    WtG[c * D_ + o] = W_g[o * D_ + c];
  } else {
    WtR[(c - D_) * D_ + o] = acc;
  }

  __shared__ float red[256];
  red[c] = (c >= D_) ? acc : 0.f;
  __syncthreads();
  for (int s = 128; s > 0; s >>= 1) {
    if (c < s) red[c] += red[c + s];
    __syncthreads();
  }
  const float padsum = red[0];
  __syncthreads();
  red[c] = (c < D_) ? W_f[o * D_ + c] * b_lin[c] : 0.f;
  __syncthreads();
  for (int s = 128; s > 0; s >>= 1) {
    if (c < s) red[c] += red[c + s];
    __syncthreads();
  }
  if (c == 0) {
    const float bc = b_f[o] + red[0];
    bcomb[o] = bc;
    bp[o] = bc + pad[0] * padsum;
  }
}

// ---------------------------------------------------------------------------
// prepB: Wgr_kn[c*128+o] = sum_d WtR[d*128+o]*W_g[d*128+c]; bgr = WtR^T b_g
// ---------------------------------------------------------------------------
__global__ __launch_bounds__(128) void prepB_kernel(
    const float* __restrict__ WtR, const float* __restrict__ W_g,
    const float* __restrict__ b_g, float* __restrict__ Wgr_kn,
    float* __restrict__ bgr) {
  const int o = blockIdx.x;
  const int c = threadIdx.x;
  float acc = 0.f;
#pragma unroll 4
  for (int d = 0; d < D_; ++d) acc += WtR[d * D_ + o] * W_g[d * D_ + c];
  Wgr_kn[c * D_ + o] = acc;

  __shared__ float red[128];
  red[c] = WtR[c * D_ + o] * b_g[c];
  __syncthreads();
  for (int s = 64; s > 0; s >>= 1) {
    if (c < s) red[c] += red[c + s];
    __syncthreads();
  }
  if (c == 0) bgr[o] = red[0];
}

// ---------------------------------------------------------------------------
// prep2 (x3 fused): pack [k][n] fp32 weights into bf16 hi/lo B-fragments.
// ---------------------------------------------------------------------------
__global__ __launch_bounds__(64) void prep2_kernel(
    const float* __restrict__ W0, const float* __restrict__ W1,
    const float* __restrict__ W2, ushort* __restrict__ B0,
    ushort* __restrict__ B1, ushort* __restrict__ B2) {
  const float* Wkn = blockIdx.y == 0 ? W0 : (blockIdx.y == 1 ? W1 : W2);
  ushort* Bpack    = blockIdx.y == 0 ? B0 : (blockIdx.y == 1 ? B1 : B2);
  const int fi = blockIdx.x;          // 0..63
  const int l = threadIdx.x;          // 0..63
  const int ishi = (fi >> 5) ^ 1;     // fi<32 -> hi
  const int k0 = (fi >> 3) & 3;
  const int n0 = fi & 7;
  const int o = n0 * 16 + (l & 15);
  const int kb = k0 * 32 + ((l >> 4) & 3) * 8;
  ushort* dst = Bpack + ((size_t)fi * 64 + l) * 8;
#pragma unroll
  for (int j = 0; j < 8; ++j) {
    const float w = Wkn[(size_t)(kb + j) * D_ + o];
    const ushort h = f2bf(w);
    if (ishi) {
      dst[j] = h;
    } else {
      dst[j] = f2bf(w - bf2f(h));
    }
  }
}

// ---------------------------------------------------------------------------
// scatter: last-e-wins per grid cell (deterministic via atomicMax on e)
// ---------------------------------------------------------------------------
__global__ __launch_bounds__(256) void scatter_kernel(
    const int* __restrict__ nodes, int* __restrict__ winner) {
  const int e = blockIdx.x * 256 + threadIdx.x;
  if (e < E_) {
    const int n0 = nodes[e * 2 + 0];
    const int n1 = nodes[e * 2 + 1];
    atomicMax(&winner[(n0 - 1) * N_ + (n1 - 1)], e);
  }
}

// ---------------------------------------------------------------------------
// mean over t of x
// ---------------------------------------------------------------------------
__global__ __launch_bounds__(256) void mean_kernel(
    const float* __restrict__ x, float* __restrict__ xmean) {
  const int idx = blockIdx.x * 256 + threadIdx.x;   // 0 .. EB*32-1
  const int pair = idx >> 5;
  const int o4 = (idx & 31) * 4;
  const size_t base = (size_t)pair * D_ + o4;
  float4 s = *(const float4*)&x[base];
  const float4 v1 = *(const float4*)&x[base + (size_t)1 * XSTRIDE_T];
  const float4 v2 = *(const float4*)&x[base + (size_t)2 * XSTRIDE_T];
  const float4 v3 = *(const float4*)&x[base + (size_t)3 * XSTRIDE_T];
  s.x = (s.x + v1.x + v2.x + v3.x) * 0.25f;
  s.y = (s.y + v1.y + v2.y + v3.y) * 0.25f;
  s.z = (s.z + v1.z + v2.z + v3.z) * 0.25f;
  s.w = (s.w + v1.w + v2.w + v3.w) * 0.25f;
  *(float4*)&xmean[base] = s;
}

// ---------------------------------------------------------------------------
// mega2: all three GEMMs, block-cooperative 32-row tiles, single 16KB LDS
// buffer, reg-staged prefetch pipeline, 2x2 wave split of the output.
//   t <  1024          : out_x = x @ WgT + b_g
//   1024 <= t < 1280   : uc    = xmean @ Wgr + bgr
//   t >= 1280          : out_feats = feats @ WcombL + bp
// grid 2624 = TTOT/4 exactly: 4 tiles/block, 8 resident blocks/CU.
// ---------------------------------------------------------------------------
__global__ __launch_bounds__(256, 4) void mega2_kernel(
    const float* __restrict__ x, const float* __restrict__ xmean,
    const float* __restrict__ feats,
    const ushort* __restrict__ BpG, const ushort* __restrict__ BpR,
    const ushort* __restrict__ BpL,
    const float* __restrict__ b_g, const float* __restrict__ bgr,
    const float* __restrict__ bpv,
    float* __restrict__ out_x, float* __restrict__ ucv,
    float* __restrict__ out_feats) {
  __shared__ float lw[4096];               // 16 KB: 32 rows x 128, swizzled
  const int tid = threadIdx.x;
  const int wave = tid >> 6, lane = tid & 63;
  const int l15 = lane & 15, lh = (lane >> 4) & 3;
  const int rh = (wave & 1) * 16;          // row half owned by this wave
  const int nb = (wave >> 1) * 4;          // n0 base (col half)
  constexpr int GRID = 2624;
  constexpr int TT0 = XROWS / 32;                 // 1024
  constexpr int TT1 = EB / 32;                    // 256
  constexpr int TTOT = TT0 + TT1 + NROWS / 32;    // 10496 = 4*GRID

  const int bid = blockIdx.x;
  int t = (bid & 7) * (GRID / 8) + (bid >> 3);    // XCD swizzle (2624%8==0)

  float4 pf[4];
  {  // prologue prefetch A(t)
    const float* As; int r0;
    if (t < TT0)            { As = x;     r0 = t * 32; }
    else if (t < TT0 + TT1) { As = xmean; r0 = (t - TT0) * 32; }
    else                    { As = feats; r0 = (t - TT0 - TT1) * 32; }
#pragma unroll
    for (int r = 0; r < 4; ++r) {
      const int idx = r * 256 + tid;
      pf[r] = *(const float4*)&As[((size_t)r0 + (idx >> 5)) * D_ + (idx & 31) * 4];
    }
  }

  while (t < TTOT) {
    const ushort* Bp; const float* bias; float* Dst; int r0;
    if (t < TT0)            { Bp = BpG; bias = b_g; Dst = out_x;     r0 = t * 32; }
    else if (t < TT0 + TT1) { Bp = BpR; bias = bgr; Dst = ucv;       r0 = (t - TT0) * 32; }
    else                    { Bp = BpL; bias = bpv; Dst = out_feats; r0 = (t - TT0 - TT1) * 32; }

    __syncthreads();   // (d) buf free: prev tile's C-store LDS reads done
#pragma unroll
    for (int r = 0; r < 4; ++r) {   // stage A(t) regs -> swizzled LDS
      const int idx = r * 256 + tid;
      const int row = idx >> 5, c4 = idx & 31;
      *(float4*)&lw[(row * 128 + c4 * 4) ^ ((row & 7) << 2)] = pf[r];
    }
    const int tn = t + GRID;
    if (tn < TTOT) {   // async prefetch A(tn); flies during compute
      const float* As; int r2;
      if (tn < TT0)            { As = x;     r2 = tn * 32; }
      else if (tn < TT0 + TT1) { As = xmean; r2 = (tn - TT0) * 32; }
      else                     { As = feats; r2 = (tn - TT0 - TT1) * 32; }
#pragma unroll
      for (int r = 0; r < 4; ++r) {
        const int idx = r * 256 + tid;
        pf[r] = *(const float4*)&As[((size_t)r2 + (idx >> 5)) * D_ + (idx & 31) * 4];
      }
    }
    __syncthreads();   // (a) A(t) visible to all waves

    f32x4 acc[4];
#pragma unroll
    for (int n0 = 0; n0 < 4; ++n0) {
      const float b = bias[(nb + n0) * 16 + l15];
      acc[n0][0] = b; acc[n0][1] = b; acc[n0][2] = b; acc[n0][3] = b;
    }
    const bf16x8* __restrict__ bp8 = (const bf16x8*)Bp;
#pragma unroll
    for (int k0 = 0; k0 < 4; ++k0) {
      bf16x8 bh[4], bl[4];
#pragma unroll
      for (int n0 = 0; n0 < 4; ++n0) {
        bh[n0] = bp8[(size_t)((k0 * 8 + nb + n0) * 64 + lane)];
        bl[n0] = bp8[(size_t)((32 + k0 * 8 + nb + n0) * 64 + lane)];
      }
      const int row = rh + l15;
      const int fb = row * 128 + lh * 8 + k0 * 32;
      const int sw = (row & 7) << 2;
      const float4 a0 = *(const float4*)&lw[(fb + 0) ^ sw];
      const float4 a1 = *(const float4*)&lw[(fb + 4) ^ sw];
      const float xs[8] = {a0.x, a0.y, a0.z, a0.w, a1.x, a1.y, a1.z, a1.w};
      BF8 ah, al;
#pragma unroll
      for (int j = 0; j < 8; ++j) {
        const ushort h = f2bf(xs[j]);
        ah.u[j] = h;
        al.u[j] = f2bf(xs[j] - bf2f(h));
      }
#pragma unroll
      for (int n0 = 0; n0 < 4; ++n0) {
        acc[n0] = __builtin_amdgcn_mfma_f32_16x16x32_bf16(ah.v, bh[n0], acc[n0], 0, 0, 0);
        acc[n0] = __builtin_amdgcn_mfma_f32_16x16x32_bf16(al.v, bh[n0], acc[n0], 0, 0, 0);
        acc[n0] = __builtin_amdgcn_mfma_f32_16x16x32_bf16(ah.v, bl[n0], acc[n0], 0, 0, 0);
      }
    }
    __syncthreads();   // (b) all waves done reading A(t)

#pragma unroll
    for (int n0 = 0; n0 < 4; ++n0) {   // C -> swizzled LDS (transpose)
      const int col = (nb + n0) * 16 + l15;
#pragma unroll
      for (int i = 0; i < 4; ++i) {
        const int row = rh + lh * 4 + i;
        lw[(row * 128 + col) ^ ((row & 7) << 2)] = acc[n0][i];
      }
    }
    __syncthreads();   // (c) C visible
#pragma unroll
    for (int r = 0; r < 4; ++r) {      // fully coalesced stores
      const int idx = r * 256 + tid;
      const int row = idx >> 5, c4 = idx & 31;
      const float4 v =
          *(const float4*)&lw[(row * 128 + c4 * 4) ^ ((row & 7) << 2)];
      *(float4*)&Dst[((size_t)r0 + row) * D_ + c4 * 4] = v;
    }
    t = tn;
  }
}

// ---------------------------------------------------------------------------
// fixup: winner rows: out_feats[cell*2+b][o] += uc[e*2+b][o] + bcomb[o]-bp[o]
// ---------------------------------------------------------------------------
__global__ __launch_bounds__(256) void fixup_kernel(
    const int* __restrict__ nodes, const int* __restrict__ winner,
    const float* __restrict__ uc, const float* __restrict__ bcomb,
    const float* __restrict__ bp, float* __restrict__ out_feats) {
  const int e = blockIdx.x;
  const int n0 = nodes[e * 2 + 0] - 1;
  const int n1 = nodes[e * 2 + 1] - 1;
  const int cell = n0 * N_ + n1;
  if (winner[cell] != e) return;
  const int t = threadIdx.x;
  const int b = t >> 7, o = t & 127;
  out_feats[((size_t)cell * 2 + b) * D_ + o] +=
      uc[((size_t)e * 2 + b) * D_ + o] + bcomb[o] - bp[o];
}

// ---------------------------------------------------------------------------
// gather_add: out_x[t,e,b,:] += out_feats[n0-1, n1-1, b, :]
// ---------------------------------------------------------------------------
__global__ __launch_bounds__(256) void gather_add_kernel(
    const int* __restrict__ nodes, const float* __restrict__ out_feats,
    float* __restrict__ out_x) {
  const int e = blockIdx.x;
  const int tid = threadIdx.x;
  const int b = tid >> 7, o = tid & 127;
  const int n0 = nodes[((size_t)b * E_ + e) * 2 + 0] - 1;
  const int n1 = nodes[((size_t)b * E_ + e) * 2 + 1] - 1;
  const float fs = out_feats[(((size_t)n0 * N_ + n1) * B_ + b) * D_ + o];
#pragma unroll
  for (int t = 0; t < T_; ++t)
    out_x[(((size_t)t * E_ + e) * B_ + b) * D_ + o] += fs;
}

// ---------------------------------------------------------------------------
extern "C" void kernel_launch(void* const* d_in, const int* in_sizes, int n_in,
                              void* d_out, int out_size, void* d_ws, size_t ws_size,
                              hipStream_t stream) {
  const float* x      = (const float*)d_in[0];
  const float* feats  = (const float*)d_in[1];
  const int*   nodes  = (const int*)d_in[2];
  const float* pad    = (const float*)d_in[5];
  const float* W_g    = (const float*)d_in[6];
  const float* b_g    = (const float*)d_in[7];
  const float* W_lin  = (const float*)d_in[8];
  const float* b_lin  = (const float*)d_in[9];
  const float* W_f    = (const float*)d_in[10];
  const float* b_f    = (const float*)d_in[11];

  float* out_x     = (float*)d_out;                       // T*E*B*D
  float* out_feats = out_x + (size_t)T_ * E_ * B_ * D_;   // N*N*B*D

  if (ws_size < WS_FLOATS * sizeof(float) + 16) return;

  float*  wsf    = (float*)d_ws;
  float*  WtG    = wsf + OFF_WTG;
  float*  WtL    = wsf + OFF_WTL;
  float*  WtR    = wsf + OFF_WTR;
  float*  bcomb  = wsf + OFF_BCOMB;
  float*  bpv    = wsf + OFF_BP;
  float*  xmean  = wsf + OFF_XMEAN;
  float*  uc     = wsf + OFF_UC;
  int*    win    = (int*)(wsf + OFF_WIN);
  ushort* Bpack  = (ushort*)(wsf + OFF_BPACK);
  ushort* BpackG = (ushort*)(wsf + OFF_BPACKG);
  ushort* BpackR = (ushort*)(wsf + OFF_BPACKR);
  float*  WgrKn  = wsf + OFF_WGR;
  float*  bgr    = wsf + OFF_BGR;

  prep_kernel<<<dim3(128), dim3(256), 0, stream>>>(W_f, W_lin, W_g, b_lin, b_f,
                                                   pad, WtG, WtL, WtR, bcomb,
                                                   bpv, win);
  prepB_kernel<<<dim3(128), dim3(128), 0, stream>>>(WtR, W_g, b_g, WgrKn, bgr);
  prep2_kernel<<<dim3(64, 3), dim3(64), 0, stream>>>(WtL, WtG, WgrKn, Bpack,
                                                     BpackG, BpackR);
  scatter_kernel<<<dim3(E_ / 256), dim3(256), 0, stream>>>(nodes, win);
  mean_kernel<<<dim3(EB * 32 / 256), dim3(256), 0, stream>>>(x, xmean);

  mega2_kernel<<<dim3(2624), dim3(256), 0, stream>>>(
      x, xmean, feats, BpackG, BpackR, Bpack, b_g, bgr, bpv, out_x, uc,
      out_feats);
  fixup_kernel<<<dim3(E_), dim3(256), 0, stream>>>(nodes, win, uc, bcomb, bpv,
                                                   out_feats);
  gather_add_kernel<<<dim3(E_), dim3(256), 0, stream>>>(nodes, out_feats,
                                                        out_x);
}